// Round 15
// baseline (192.363 us; speedup 1.0000x reference)
//
#include <hip/hip_runtime.h>

typedef unsigned short ushort_t;
typedef __attribute__((ext_vector_type(8))) short bf16x8;
typedef __attribute__((ext_vector_type(8))) unsigned short u16x8;
typedef __attribute__((ext_vector_type(4))) float f32x4;

#define B_ 64
#define N_ 1024
#define C_ 128

static __device__ __forceinline__ unsigned short f2bf(float f) {  // RNE
  union { float f; unsigned int i; } v; v.f = f;
  unsigned int i = v.i;
  return (unsigned short)((i + 0x7FFFu + ((i >> 16) & 1u)) >> 16);
}
// truncation split: x = hi + lo + eps, |eps| <= 2^-17 |x|
static __device__ __forceinline__ void split1(float x, ushort_t& h, ushort_t& l) {
  union { float f; unsigned int i; } u; u.f = x;
  h = (ushort_t)(u.i >> 16);
  union { unsigned int i; float f; } t; t.i = u.i & 0xFFFF0000u;
  union { float f; unsigned int i; } w; w.f = x - t.f;
  l = (ushort_t)(w.i >> 16);
}
static __device__ __forceinline__ bf16x8 as_bf(u16x8 v) {
  union { u16x8 u; bf16x8 b; } x; x.u = v; return x.b;
}
static __device__ __forceinline__ void gload_lds16(const void* g, void* l) {
  __builtin_amdgcn_global_load_lds((const __attribute__((address_space(1))) void*)g,
                                   (__attribute__((address_space(3))) void*)l,
                                   16, 0, 0);
}

// T4 counted-wait barrier: leave N VMEM ops in flight across the barrier.
#define PIPE_BAR(N) asm volatile("s_waitcnt vmcnt(" #N ")\n\ts_barrier" ::: "memory")
// post-compute reuse guard (no vmcnt drain)
#define POST_BAR()  asm volatile("s_waitcnt lgkmcnt(0)\n\ts_barrier" ::: "memory")

// ---------------------------------------------------------------------------
// Transpose + split: src fp32 [rows][cols] -> dh/dl bf16 [cols][rows]
// ---------------------------------------------------------------------------
__global__ __launch_bounds__(256) void tsplit(const float* __restrict__ src,
                                              ushort_t* __restrict__ dh,
                                              ushort_t* __restrict__ dl,
                                              int rows, int cols, long sb, long db) {
  __shared__ float tile[64][65];
  const int t = threadIdx.x;
  src += (long)blockIdx.z * sb;
  dh  += (long)blockIdx.z * db;
  dl  += (long)blockIdx.z * db;
  const int r0 = blockIdx.y * 64, c0 = blockIdx.x * 64;
#pragma unroll
  for (int p = 0; p < 4; ++p) {
    int row = p * 16 + (t >> 4), c4 = (t & 15) * 4;
    f32x4 v = *(const f32x4*)(src + (long)(r0 + row) * cols + c0 + c4);
#pragma unroll
    for (int j = 0; j < 4; ++j) tile[row][c4 + j] = v[j];
  }
  __syncthreads();
  const int oc = t >> 2;
#pragma unroll
  for (int p = 0; p < 2; ++p) {
    int ck = (t & 3) + p * 4;
    u16x8 vh, vl;
#pragma unroll
    for (int j = 0; j < 8; ++j) {
      ushort_t hj, lj;
      split1(tile[ck * 8 + j][oc], hj, lj);
      vh[j] = hj; vl[j] = lj;
    }
    long o = (long)(c0 + oc) * rows + r0 + ck * 8;
    *(u16x8*)(dh + o) = vh;
    *(u16x8*)(dl + o) = vl;
  }
}

// ---------------------------------------------------------------------------
// GC GEMM (r12-r14 verified counted-vmcnt structure, unchanged) -> vbuf.
// ---------------------------------------------------------------------------
__global__ __launch_bounds__(256, 2) void gc_gemm(const float* __restrict__ adj,
                                                  const ushort_t* __restrict__ annTh,
                                                  const ushort_t* __restrict__ annTl,
                                                  const float* __restrict__ gcb,
                                                  float* __restrict__ vout) {
  __shared__ __align__(16) float lds_all[2 * 8192];  // 2 x 32 KB staging

  const int tid = threadIdx.x;
  const int w = tid >> 6, lane = tid & 63;
  const int wr = w >> 1, wc = w & 1;
  const int swz = (blockIdx.x & 7) * 64 + (blockIdx.x >> 3);
  const int b = swz >> 3;
  const int m0 = (swz & 7) * 128;

  const float*    adjb = adj   + ((long)b * N_ + m0) * N_;
  const ushort_t* aThb = annTh + (long)b * C_ * N_;
  const ushort_t* aTlb = annTl + (long)b * C_ * N_;

  const int fr = lane & 15;
  const int kg = lane >> 4;
  const int aRow = lane >> 3;
  const int aCs  = (lane & 7) ^ aRow;
  const int bRow = lane >> 2;
  const int bCs  = (lane & 3) ^ ((lane >> 3) & 3);

  f32x4 acc[4][4] = {};

#define STAGE(Q, T)                                                            \
  {                                                                            \
    const int k0_ = (T) * 32;                                                  \
    float*    A_  = lds_all + (Q) * 8192;                                      \
    ushort_t* Bh_ = (ushort_t*)(lds_all + (Q) * 8192 + 4096);                  \
    ushort_t* Bl_ = (ushort_t*)(lds_all + (Q) * 8192 + 6144);                  \
    _Pragma("unroll")                                                          \
    for (int jj = 0; jj < 4; ++jj) {                                           \
      int j_ = w * 4 + jj;                                                     \
      gload_lds16(adjb + (long)(j_ * 8 + aRow) * N_ + k0_ + aCs * 4,           \
                  (void*)(A_ + j_ * 256));                                     \
    }                                                                          \
    _Pragma("unroll")                                                          \
    for (int jj = 0; jj < 2; ++jj) {                                           \
      int j_ = w * 2 + jj;                                                     \
      long so_ = (long)(j_ * 16 + bRow) * N_ + k0_ + bCs * 8;                  \
      gload_lds16(aThb + so_, (void*)(Bh_ + j_ * 512));                        \
      gload_lds16(aTlb + so_, (void*)(Bl_ + j_ * 512));                        \
    }                                                                          \
  }

#define COMPUTE(Q)                                                             \
  {                                                                            \
    const float*    A_  = lds_all + (Q) * 8192;                                \
    const ushort_t* Bh_ = (const ushort_t*)(lds_all + (Q) * 8192 + 4096);      \
    const ushort_t* Bl_ = (const ushort_t*)(lds_all + (Q) * 8192 + 6144);      \
    bf16x8 bh_[4], bl_[4], ah_[4], al_[4];                                     \
    _Pragma("unroll")                                                          \
    for (int ni = 0; ni < 4; ++ni) {                                           \
      int row_ = wc * 64 + ni * 16 + fr;                                       \
      int kb_ = (kg << 4) ^ ((((row_) >> 1) & 3) << 4);                        \
      bh_[ni] = *(const bf16x8*)((const char*)Bh_ + row_ * 64 + kb_);          \
      bl_[ni] = *(const bf16x8*)((const char*)Bl_ + row_ * 64 + kb_);          \
    }                                                                          \
    _Pragma("unroll")                                                          \
    for (int mi = 0; mi < 4; ++mi) {                                           \
      int row_ = wr * 64 + mi * 16 + fr;                                       \
      int b0_ = row_ * 128 + ((kg * 32) ^ ((row_ & 7) << 4));                  \
      f32x4 a0_ = *(const f32x4*)((const char*)A_ + b0_);                      \
      f32x4 a1_ = *(const f32x4*)((const char*)A_ + (b0_ ^ 16));               \
      u16x8 vh_, vl_;                                                          \
      _Pragma("unroll")                                                        \
      for (int j = 0; j < 4; ++j) {                                            \
        ushort_t hj_, lj_;                                                     \
        split1(a0_[j], hj_, lj_); vh_[j] = hj_;     vl_[j] = lj_;              \
        split1(a1_[j], hj_, lj_); vh_[4 + j] = hj_; vl_[4 + j] = lj_;          \
      }                                                                        \
      ah_[mi] = as_bf(vh_); al_[mi] = as_bf(vl_);                              \
    }                                                                          \
    _Pragma("unroll")                                                          \
    for (int mi = 0; mi < 4; ++mi)                                             \
      _Pragma("unroll")                                                        \
      for (int ni = 0; ni < 4; ++ni) {                                         \
        acc[mi][ni] = __builtin_amdgcn_mfma_f32_16x16x32_bf16(ah_[mi], bh_[ni], acc[mi][ni], 0, 0, 0); \
        acc[mi][ni] = __builtin_amdgcn_mfma_f32_16x16x32_bf16(al_[mi], bh_[ni], acc[mi][ni], 0, 0, 0); \
        acc[mi][ni] = __builtin_amdgcn_mfma_f32_16x16x32_bf16(ah_[mi], bl_[ni], acc[mi][ni], 0, 0, 0); \
      }                                                                        \
  }

  STAGE(0, 0)
#pragma unroll 1
  for (int t = 0; t < 31; ++t) {
    const int cur = t & 1;
    STAGE(cur ^ 1, t + 1)
    PIPE_BAR(8);
    COMPUTE(cur)
    POST_BAR();
  }
  PIPE_BAR(0);
  COMPUTE(1)

  const long rowbase = (long)b * N_ + m0 + wr * 64;
#pragma unroll
  for (int ni = 0; ni < 4; ++ni) {
    int col = wc * 64 + ni * 16 + fr;
    float bias = gcb[col];
#pragma unroll
    for (int mi = 0; mi < 4; ++mi)
#pragma unroll
      for (int r = 0; r < 4; ++r)
        vout[(rowbase + mi * 16 + kg * 4 + r) * C_ + col] = acc[mi][ni][r] + bias;
  }
#undef STAGE
#undef COMPUTE
}

// ---------------------------------------------------------------------------
// GRU v2 — weights in LDS (shared by 8 waves), T14 async reg-staging.
// 512 threads (8 waves), 16 rows/wave, grid 512. No W regs live across MATH
// -> ~115 VGPR -> 4 waves/SIMD. LDS 36 KB: [arr3][gate3][row16][slot16],
// slot XOR-swizzled by (row&7) -> 2-way-free ds_read_b128.
// Per-accumulator MFMA order identical to r14 -> bit-identical output.
// ---------------------------------------------------------------------------
__global__ __launch_bounds__(512, 4) void gru(const float* __restrict__ v,
                                              const float* __restrict__ ann,
                                              const ushort_t* __restrict__ kTh,
                                              const ushort_t* __restrict__ kTl,
                                              const ushort_t* __restrict__ rTh,
                                              const float* __restrict__ gb,
                                              float* __restrict__ out) {
  __shared__ __align__(16) ushort_t wlds[18432];   // 36 KB weight tile

  const int tid = threadIdx.x;
  const int w = tid >> 6, lane = tid & 63;
  const long m0 = (long)blockIdx.x * 128 + w * 16;
  const int fr = lane & 15, kg = lane >> 4;
  const int frk = fr & 7;

  // ---- x/h fragments (16 rows/wave) ----
  bf16x8 xh[4], xl[4], hh[4];
#pragma unroll
  for (int kk = 0; kk < 4; ++kk) {
    long off = (m0 + fr) * (long)C_ + kk * 32 + kg * 8;
    f32x4 x0 = *(const f32x4*)(v + off);
    f32x4 x1 = *(const f32x4*)(v + off + 4);
    u16x8 th, tl;
#pragma unroll
    for (int j = 0; j < 4; ++j) {
      ushort_t hj, lj;
      split1(x0[j], hj, lj); th[j] = hj; tl[j] = lj;
      split1(x1[j], hj, lj); th[4 + j] = hj; tl[4 + j] = lj;
    }
    xh[kk] = as_bf(th); xl[kk] = as_bf(tl);
    f32x4 h0 = *(const f32x4*)(ann + off);
    f32x4 h1 = *(const f32x4*)(ann + off + 4);
    u16x8 hv;
#pragma unroll
    for (int j = 0; j < 4; ++j) { hv[j] = f2bf(h0[j]); hv[4 + j] = f2bf(h1[j]); }
    hh[kk] = as_bf(hv);
  }

  // ---- weight staging map: 2304 chunks of 16B; thread q-th chunk ----
  // chunk c -> arr=c/768, gate=(c%768)>>8, row=((c%768)&255)>>4, slot=c&15;
  // source slot pre-swizzled (involution) so reads can XOR by (row&7).
  const ushort_t* wsrc[5];
  int wdst[5];
#pragma unroll
  for (int q = 0; q < 5; ++q) {
    int c = tid + q * 512;
    int cc = (c < 2304) ? c : 0;       // inactive threads: harmless dummy
    int arr = cc / 768, rem = cc % 768;
    int gate = rem >> 8, rem2 = rem & 255, row = rem2 >> 4, sp = rem2 & 15;
    int ssrc = sp ^ (row & 7);
    const ushort_t* base = (arr == 0) ? kTh : ((arr == 1) ? kTl : rTh);
    wsrc[q] = base + (gate * 128 + row) * 128 + ssrc * 8;
    wdst[q] = cc * 16;                  // LDS byte offset (linear)
  }
  const bool act4 = (tid < 256);        // q=4 covers chunks 2048..2303

  u16x8 wreg0, wreg1, wreg2, wreg3, wreg4;

#define LOADWREG(NN)                                                           \
  {                                                                            \
    wreg0 = *(const u16x8*)(wsrc[0] + (NN) * 2048);                            \
    wreg1 = *(const u16x8*)(wsrc[1] + (NN) * 2048);                            \
    wreg2 = *(const u16x8*)(wsrc[2] + (NN) * 2048);                            \
    wreg3 = *(const u16x8*)(wsrc[3] + (NN) * 2048);                            \
    if (act4) wreg4 = *(const u16x8*)(wsrc[4] + (NN) * 2048);                  \
  }

#define DSWRITE()                                                              \
  {                                                                            \
    *(u16x8*)((char*)wlds + wdst[0]) = wreg0;                                  \
    *(u16x8*)((char*)wlds + wdst[1]) = wreg1;                                  \
    *(u16x8*)((char*)wlds + wdst[2]) = wreg2;                                  \
    *(u16x8*)((char*)wlds + wdst[3]) = wreg3;                                  \
    if (act4) *(u16x8*)((char*)wlds + wdst[4]) = wreg4;                        \
  }

  // LDS read offset: arr a, gate g, row fr, logical slot kk*4+kg
#define WOFF(A, G, KK) (((((A) * 3 + (G)) * 16 + fr) * 16 + (((KK) * 4 + kg) ^ frk)) * 16)

#define MATH(G, AK, AR)                                                        \
  {                                                                            \
    bf16x8 KH[4], KL[4], RH[4];                                                \
    _Pragma("unroll")                                                          \
    for (int kk = 0; kk < 4; ++kk) {                                           \
      KH[kk] = *(const bf16x8*)((const char*)wlds + WOFF(0, G, kk));           \
      KL[kk] = *(const bf16x8*)((const char*)wlds + WOFF(1, G, kk));           \
      RH[kk] = *(const bf16x8*)((const char*)wlds + WOFF(2, G, kk));           \
    }                                                                          \
    _Pragma("unroll")                                                          \
    for (int kk = 0; kk < 4; ++kk) {                                           \
      AK = __builtin_amdgcn_mfma_f32_16x16x32_bf16(xh[kk], KH[kk], AK, 0, 0, 0); \
      AK = __builtin_amdgcn_mfma_f32_16x16x32_bf16(xl[kk], KH[kk], AK, 0, 0, 0); \
      AK = __builtin_amdgcn_mfma_f32_16x16x32_bf16(xh[kk], KL[kk], AK, 0, 0, 0); \
    }                                                                          \
    _Pragma("unroll")                                                          \
    for (int kk = 0; kk < 4; ++kk) {                                           \
      AR = __builtin_amdgcn_mfma_f32_16x16x32_bf16(hh[kk], RH[kk], AR, 0, 0, 0); \
    }                                                                          \
  }

  // prologue: W(0) -> regs -> LDS
  LOADWREG(0)
  DSWRITE()
  __syncthreads();

#pragma unroll 1
  for (int n = 0; n < 8; ++n) {
    if (n < 7) LOADWREG(n + 1)   // issue early; lands during MATH+epilogue

    f32x4 az = {}, ar = {}, ax = {}, ah = {};
    MATH(0, az, az)
    MATH(1, ar, ar)
    MATH(2, ax, ah)

    const int cb = n * 16 + fr;
    float HV[4];
#pragma unroll
    for (int r = 0; r < 4; ++r)
      HV[r] = ann[(m0 + kg * 4 + r) * (long)C_ + cb];

    const float bz  = gb[cb] + gb[384 + cb];
    const float brr = gb[128 + cb] + gb[384 + 128 + cb];
    const float bxh = gb[256 + cb];
    const float bhi = gb[384 + 256 + cb];
#pragma unroll
    for (int r = 0; r < 4; ++r) {
      long row = m0 + kg * 4 + r;
      float zz = 1.f / (1.f + __expf(-(az[r] + bz)));
      float rr = 1.f / (1.f + __expf(-(ar[r] + brr)));
      float hpre = ax[r] + bxh + rr * (ah[r] + bhi);
      hpre = fminf(fmaxf(hpre, -15.f), 15.f);
      float e2 = __expf(2.f * hpre);
      float th = (e2 - 1.f) / (e2 + 1.f);
      out[row * C_ + cb] = zz * HV[r] + (1.f - zz) * th;
    }

    if (n < 7) {
      __syncthreads();   // all waves done reading wlds for step n
      DSWRITE()          // write W(n+1) (regs landed during compute)
      __syncthreads();   // writes visible
    }
  }
#undef LOADWREG
#undef DSWRITE
#undef WOFF
#undef MATH
}

// ---------------------------------------------------------------------------
extern "C" void kernel_launch(void* const* d_in, const int* in_sizes, int n_in,
                              void* d_out, int out_size, void* d_ws, size_t ws_size,
                              hipStream_t stream) {
  const float* adj = (const float*)d_in[0];
  const float* ann = (const float*)d_in[1];
  const float* gcb = (const float*)d_in[2];
  const float* ker = (const float*)d_in[3];
  const float* rk  = (const float*)d_in[4];
  const float* gb  = (const float*)d_in[5];
  float* out = (float*)d_out;

  char* ws = (char*)d_ws;
  ushort_t* annTh = (ushort_t*)(ws);                      // [64][128][1024] bf16, 16 MB
  ushort_t* annTl = (ushort_t*)(ws + 16777216);           // 16 MB
  ushort_t* kTh   = (ushort_t*)(ws + 33554432);           // [384][128]
  ushort_t* kTl   = (ushort_t*)(ws + 33652736);
  ushort_t* rTh   = (ushort_t*)(ws + 33751040);
  ushort_t* rTl   = (ushort_t*)(ws + 33849344);
  float*    vbuf  = (float*)(ws + 33947648);              // [65536][128] fp32, 33.5 MB

  hipLaunchKernelGGL(tsplit, dim3(2, 16, 64), dim3(256), 0, stream,
                     ann, annTh, annTl, 1024, 128, (long)1024 * 128, (long)128 * 1024);
  hipLaunchKernelGGL(tsplit, dim3(6, 2, 1), dim3(256), 0, stream,
                     ker, kTh, kTl, 128, 384, 0L, 0L);
  hipLaunchKernelGGL(tsplit, dim3(6, 2, 1), dim3(256), 0, stream,
                     rk, rTh, rTl, 128, 384, 0L, 0L);
  // graph convolution -> vbuf
  hipLaunchKernelGGL(gc_gemm, dim3(512), dim3(256), 0, stream,
                     adj, annTh, annTl, gcb, vbuf);
  // GRU step (weights in shared LDS, async-staged)
  hipLaunchKernelGGL(gru, dim3(512), dim3(512), 0, stream,
                     vbuf, ann, kTh, kTl, rTh, gb, out);
}